// Round 6
// baseline (40.300 us; speedup 1.0000x reference)
//
#include <hip/hip_runtime.h>
#include <hip/hip_bf16.h>

#define D_IN  512
#define C_OUT 128
#define HW    16384   // 128*128 per batch
#define BM    256     // rows per block = 8 waves x 32
#define NKT   16      // k-tiles of 32

typedef __attribute__((ext_vector_type(8))) short bf16x8;
typedef __attribute__((ext_vector_type(4))) float f32x4;

__device__ __forceinline__ short bf(float f) {
    return (short)__builtin_bit_cast(ushort, __float2bfloat16(f));  // RNE
}

__device__ __forceinline__ bf16x8 pack8(f32x4 a, f32x4 b) {
    bf16x8 r;
    r[0] = bf(a[0]); r[1] = bf(a[1]); r[2] = bf(a[2]); r[3] = bf(a[3]);
    r[4] = bf(b[0]); r[5] = bf(b[1]); r[6] = bf(b[2]); r[7] = bf(b[3]);
    return r;
}

__global__ __launch_bounds__(512) void cwp_gemm(
    const float* __restrict__ x, const float* __restrict__ W,
    const float* __restrict__ bias, float* __restrict__ out)
{
    // Entire W as bf16, permuted into MFMA A-fragment order:
    // tile (kt*8+ci) holds 16c x 32k; lane l's 16B at tile*1024 + l*16
    // = W[c=ci*16+(l&15)][k=kt*32+(l>>4)*8 .. +8)
    __shared__ ushort Wlds[C_OUT * D_IN];   // 128 KiB -> 1 block/CU

    const int t    = threadIdx.x;
    const int lane = t & 63;
    const int wid  = t >> 6;      // 0..7 : wave owns 32 m-rows, all 128 c
    const int q    = lane >> 4;   // 0..3
    const int lr   = lane & 15;

    const int m0   = blockIdx.x * BM;
    const int bidx = m0 / HW;
    const int hwb  = (m0 % HW) + wid * 32;       // hw base for this wave
    const size_t mbase = (size_t)m0 + wid * 32;  // absolute row base

    // x lane pointers in B-fragment layout (row = base+mt*16+lr, k-chunk q*8)
    const float* xp0 = x + (mbase + lr) * D_IN + q * 8;        // mt=0
    const float* xp1 = x + (mbase + 16 + lr) * D_IN + q * 8;   // mt=1

    // prologue x loads (kt=0) issued BEFORE W staging to overlap
    f32x4 c00 = *reinterpret_cast<const f32x4*>(xp0);
    f32x4 c01 = *reinterpret_cast<const f32x4*>(xp0 + 4);
    f32x4 c10 = *reinterpret_cast<const f32x4*>(xp1);
    f32x4 c11 = *reinterpret_cast<const f32x4*>(xp1 + 4);

    // ---- stage full W (fp32 from L2 -> bf16) into LDS, fragment-permuted ----
    #pragma unroll
    for (int s = 0; s < 16; ++s) {
        const int slot = s * 512 + t;        // 0..8191
        const int tile = slot >> 6;          // kt*8 + ci
        const int ln   = slot & 63;
        const int c    = (tile & 7) * 16 + (ln & 15);
        const int k    = (tile >> 3) * 32 + (ln >> 4) * 8;
        const f32x4 w0 = *reinterpret_cast<const f32x4*>(&W[c * D_IN + k]);
        const f32x4 w1 = *reinterpret_cast<const f32x4*>(&W[c * D_IN + k + 4]);
        *reinterpret_cast<bf16x8*>(&Wlds[slot * 8]) = pack8(w0, w1);
    }

    f32x4 acc[8][2];   // [ci][mt]
    #pragma unroll
    for (int ci = 0; ci < 8; ++ci)
        #pragma unroll
        for (int mt = 0; mt < 2; ++mt)
            acc[ci][mt] = (f32x4){0.f, 0.f, 0.f, 0.f};

    __syncthreads();   // the ONLY barrier: W ready; K-loop below is barrier-free

    #pragma unroll
    for (int kt = 0; kt < NKT; ++kt) {
        // prefetch next k-tile's x (1-ahead; hides under 16 MFMAs + ds_reads)
        f32x4 n00 = c00, n01 = c01, n10 = c10, n11 = c11;
        if (kt + 1 < NKT) {
            const int ko = (kt + 1) * 32;
            n00 = *reinterpret_cast<const f32x4*>(xp0 + ko);
            n01 = *reinterpret_cast<const f32x4*>(xp0 + ko + 4);
            n10 = *reinterpret_cast<const f32x4*>(xp1 + ko);
            n11 = *reinterpret_cast<const f32x4*>(xp1 + ko + 4);
        }

        const bf16x8 b0 = pack8(c00, c01);
        const bf16x8 b1 = pack8(c10, c11);

        #pragma unroll
        for (int ci = 0; ci < 8; ++ci) {
            const bf16x8 a =
                *reinterpret_cast<const bf16x8*>(&Wlds[((kt * 8 + ci) * 64 + lane) * 8]);
            acc[ci][0] = __builtin_amdgcn_mfma_f32_16x16x32_bf16(a, b0, acc[ci][0], 0, 0, 0);
            acc[ci][1] = __builtin_amdgcn_mfma_f32_16x16x32_bf16(a, b1, acc[ci][1], 0, 0, 0);
        }

        c00 = n00; c01 = n01; c10 = n10; c11 = n11;
    }

    // ---- epilogue: D row = c-local (q*4+jj), col = m-local (lr) ----
    float* outb = out + (size_t)bidx * C_OUT * HW;
    #pragma unroll
    for (int ci = 0; ci < 8; ++ci) {
        #pragma unroll
        for (int jj = 0; jj < 4; ++jj) {
            const int c  = ci * 16 + q * 4 + jj;
            const float bv = bias[c];
            outb[(size_t)c * HW + hwb + lr]      = acc[ci][0][jj] + bv;
            outb[(size_t)c * HW + hwb + 16 + lr] = acc[ci][1][jj] + bv;
        }
    }
}

extern "C" void kernel_launch(void* const* d_in, const int* in_sizes, int n_in,
                              void* d_out, int out_size, void* d_ws, size_t ws_size,
                              hipStream_t stream) {
    const float* x    = (const float*)d_in[0];
    const float* W    = (const float*)d_in[1];
    const float* b    = (const float*)d_in[2];
    float* out        = (float*)d_out;
    const int M = 4 * HW;              // 65536 rows
    dim3 grid(M / BM);                 // 256 blocks = 1 per CU
    cwp_gemm<<<grid, 512, 0, stream>>>(x, W, b, out);
}

// Round 7
// 29.800 us; speedup vs baseline: 1.3524x; 1.3524x over previous
//
#include <hip/hip_runtime.h>
#include <hip/hip_bf16.h>

#define D_IN  512
#define C_OUT 128
#define HW    16384   // 128*128 per batch
#define BM    128
#define BK    64
#define PAD   72      // 144B row stride -> 2-way LDS aliasing on b128 reads (free, m136)

typedef __attribute__((ext_vector_type(8))) short bf16x8;
typedef __attribute__((ext_vector_type(4))) float f32x4;

__device__ __forceinline__ ushort bf(float f) {
    // scalar cast -> compiler emits packed v_cvt_pk_bf16_f32 (RNE), per m240
    return __builtin_bit_cast(ushort, __float2bfloat16(f));
}

__global__ __launch_bounds__(256) void cwp_gemm(
    const float* __restrict__ x, const float* __restrict__ W,
    const float* __restrict__ bias, float* __restrict__ out)
{
    __shared__ ushort Ws[C_OUT * PAD];   // W tile  [c][k], bf16
    __shared__ ushort Xs[BM * PAD];      // x tile  [m][k], bf16

    const int t    = threadIdx.x;
    const int lane = t & 63;
    const int wid  = t >> 6;     // 0..3
    const int wr   = wid >> 1;   // c-half of block tile
    const int wc   = wid & 1;    // m-half of block tile
    const int q    = lane >> 4;  // 0..3
    const int lr   = lane & 15;

    const int m0   = blockIdx.x * BM;
    const int bidx = m0 / HW;
    const int hw0  = m0 % HW;

    f32x4 acc[4][4];
    #pragma unroll
    for (int i = 0; i < 4; ++i)
        #pragma unroll
        for (int j = 0; j < 4; ++j)
            acc[i][j] = (f32x4){0.f, 0.f, 0.f, 0.f};

    const int srow = t >> 4;  // 0..15: row-within-pass
    const int scol = t & 15;  // f32x4 column within BK

    for (int kt = 0; kt < D_IN; kt += BK) {
        // ---- load stage: 8 f32x4 of W + 8 f32x4 of x per thread ----
        f32x4 wv[8], xv[8];
        #pragma unroll
        for (int p = 0; p < 8; ++p) {
            const int r = p * 16 + srow;  // covers 128 rows
            wv[p] = *reinterpret_cast<const f32x4*>(&W[r * D_IN + kt + scol * 4]);
            xv[p] = *reinterpret_cast<const f32x4*>(&x[(size_t)(m0 + r) * D_IN + kt + scol * 4]);
        }
        __syncthreads();  // previous tile's compute done before LDS overwrite
        #pragma unroll
        for (int p = 0; p < 8; ++p) {
            const int r = p * 16 + srow;
            ushort4 wp = make_ushort4(bf(wv[p][0]), bf(wv[p][1]), bf(wv[p][2]), bf(wv[p][3]));
            ushort4 xp = make_ushort4(bf(xv[p][0]), bf(xv[p][1]), bf(xv[p][2]), bf(xv[p][3]));
            *reinterpret_cast<ushort4*>(&Ws[r * PAD + scol * 4]) = wp;
            *reinterpret_cast<ushort4*>(&Xs[r * PAD + scol * 4]) = xp;
        }
        __syncthreads();

        // ---- compute: 2 k-subs x 16 MFMA per wave ----
        #pragma unroll
        for (int ks = 0; ks < 2; ++ks) {
            bf16x8 af[4], bfv[4];
            #pragma unroll
            for (int i = 0; i < 4; ++i) {
                af[i]  = *reinterpret_cast<const bf16x8*>(&Ws[(wr*64 + i*16 + lr) * PAD + ks*32 + q*8]);
                bfv[i] = *reinterpret_cast<const bf16x8*>(&Xs[(wc*64 + i*16 + lr) * PAD + ks*32 + q*8]);
            }
            #pragma unroll
            for (int i = 0; i < 4; ++i)
                #pragma unroll
                for (int j = 0; j < 4; ++j)
                    acc[i][j] = __builtin_amdgcn_mfma_f32_16x16x32_bf16(af[i], bfv[j], acc[i][j], 0, 0, 0);
        }
    }

    // ---- epilogue: D[row=c-local][col=m-local]; row=(lane>>4)*4+jj, col=lane&15 ----
    float bv[4][4];
    #pragma unroll
    for (int i = 0; i < 4; ++i)
        #pragma unroll
        for (int jj = 0; jj < 4; ++jj)
            bv[i][jj] = bias[wr*64 + i*16 + q*4 + jj];

    float* outb = out + (size_t)bidx * C_OUT * HW;
    #pragma unroll
    for (int i = 0; i < 4; ++i) {
        const int c0 = wr*64 + i*16 + q*4;
        #pragma unroll
        for (int j = 0; j < 4; ++j) {
            const int m = hw0 + wc*64 + j*16 + lr;
            #pragma unroll
            for (int jj = 0; jj < 4; ++jj)
                outb[(size_t)(c0 + jj) * HW + m] = acc[i][j][jj] + bv[i][jj];
        }
    }
}

extern "C" void kernel_launch(void* const* d_in, const int* in_sizes, int n_in,
                              void* d_out, int out_size, void* d_ws, size_t ws_size,
                              hipStream_t stream) {
    const float* x    = (const float*)d_in[0];
    const float* W    = (const float*)d_in[1];
    const float* b    = (const float*)d_in[2];
    float* out        = (float*)d_out;
    const int M = 4 * HW;              // 65536 rows
    dim3 grid(M / BM);                 // 512 blocks, 2 per CU
    cwp_gemm<<<grid, 256, 0, stream>>>(x, W, b, out);
}